// Round 1
// baseline (60.993 us; speedup 1.0000x reference)
//
#include <hip/hip_runtime.h>

#define NSPIN   64
#define BATCH_N 1000000
#define NTILES  (BATCH_N / 16)   // 62500 16-row tiles

typedef __bf16 bf16x8 __attribute__((ext_vector_type(8)));
typedef float  f32x4  __attribute__((ext_vector_type(4)));

// Build symmetric bf16 J (zero diag) from lower-tri coupling vector.
// tril_indices(k=-1) row-major: element t of couplings -> (r,c) with
// offset(r) = r*(r-1)/2, c in [0,r). Forward map per (r,c) needs no sqrt.
__global__ void build_J_kernel(const float* __restrict__ couplings,
                               __bf16* __restrict__ Jg) {
    int idx = blockIdx.x * blockDim.x + threadIdx.x;
    if (idx >= NSPIN * NSPIN) return;
    int r = idx >> 6, c = idx & 63;
    float v = 0.0f;
    if (r > c)      v = couplings[(r * (r - 1)) / 2 + c];
    else if (r < c) v = couplings[(c * (c - 1)) / 2 + r];
    Jg[idx] = (__bf16)v;
}

__device__ __forceinline__ unsigned fbits(float x) {
    union { float f; unsigned u; } cv; cv.f = x; return cv.u;
}
// pack two fp32 into packed bf16x2 (truncation — exact for +/-1.0)
__device__ __forceinline__ unsigned pack2(float lo, float hi) {
    // result = hi16(hi)<<16 | hi16(lo)
    return __builtin_amdgcn_perm(fbits(hi), fbits(lo), 0x07060302u);
}

template<bool USE_WS>
__global__ __launch_bounds__(256, 4) void ham_kernel(
    const float* __restrict__ states,
    const float* __restrict__ couplings,
    const float* __restrict__ fields,
    const __bf16* __restrict__ Jg,
    float* __restrict__ out,
    int num_waves)
{
    __shared__ bf16x8 Jlds[NSPIN * NSPIN / 8];   // 8 KB, used only if !USE_WS
    if constexpr (!USE_WS) {
        __bf16* J = (__bf16*)Jlds;
        for (int i = threadIdx.x; i < NSPIN * NSPIN; i += 256) {
            int r = i >> 6, c = i & 63;
            float v = 0.0f;
            if (r > c)      v = couplings[(r * (r - 1)) / 2 + c];
            else if (r < c) v = couplings[(c * (c - 1)) / 2 + r];
            J[i] = (__bf16)v;
        }
        __syncthreads();
    }

    const int lane = threadIdx.x & 63;
    const int wid  = threadIdx.x >> 6;
    const int lo16 = lane & 15;   // col for B/D, row for A
    const int g4   = lane >> 4;   // k-group / D-row group
    const int gw   = blockIdx.x * 4 + wid;

    // B operand fragments (hoisted): jf[nb][kb] must hold
    // J[k = kb*32 + g4*8 + b][n = nb*16 + lo16]; J symmetric ->
    // = J[n][k], i.e. 8 contiguous bf16 of row n. 16B-aligned.
    bf16x8 jf[4][2];
#pragma unroll
    for (int nb = 0; nb < 4; ++nb)
#pragma unroll
        for (int kb = 0; kb < 2; ++kb) {
            int off = (nb * 16 + lo16) * NSPIN + kb * 32 + g4 * 8;
            if constexpr (USE_WS) jf[nb][kb] = *reinterpret_cast<const bf16x8*>(Jg + off);
            else                  jf[nb][kb] = Jlds[off / 8];
        }

    // Field value for this lane's D-column (same for all 4 row-regs).
    float fcol[4];
#pragma unroll
    for (int nb = 0; nb < 4; ++nb) fcol[nb] = fields[nb * 16 + lo16];

    for (int t = gw; t < NTILES; t += num_waves) {
        const float* S = states + (size_t)t * (16 * NSPIN);

        // A fragments: A[row = lo16][k = kb*32 + g4*8 + b], 8 consecutive
        // fp32 per kb, 2x dwordx4 each. Whole wave covers the 4KB tile once.
        const float* arow = S + lo16 * NSPIN + g4 * 8;
        f32x4 a0 = *reinterpret_cast<const f32x4*>(arow);       // kb=0
        f32x4 a1 = *reinterpret_cast<const f32x4*>(arow + 4);
        f32x4 a2 = *reinterpret_cast<const f32x4*>(arow + 32);  // kb=1
        f32x4 a3 = *reinterpret_cast<const f32x4*>(arow + 36);

        union { bf16x8 v; unsigned u[4]; } af0, af1;
        af0.u[0] = pack2(a0[0], a0[1]);
        af0.u[1] = pack2(a0[2], a0[3]);
        af0.u[2] = pack2(a1[0], a1[1]);
        af0.u[3] = pack2(a1[2], a1[3]);
        af1.u[0] = pack2(a2[0], a2[1]);
        af1.u[1] = pack2(a2[2], a2[3]);
        af1.u[2] = pack2(a3[0], a3[1]);
        af1.u[3] = pack2(a3[2], a3[3]);

        // acc init = f[col]: D = S*J + f  (field folded in for free)
        f32x4 acc[4];
#pragma unroll
        for (int nb = 0; nb < 4; ++nb)
            acc[nb] = (f32x4){fcol[nb], fcol[nb], fcol[nb], fcol[nb]};
#pragma unroll
        for (int nb = 0; nb < 4; ++nb) {
            acc[nb] = __builtin_amdgcn_mfma_f32_16x16x32_bf16(af0.v, jf[nb][0], acc[nb], 0, 0, 0);
            acc[nb] = __builtin_amdgcn_mfma_f32_16x16x32_bf16(af1.v, jf[nb][1], acc[nb], 0, 0, 0);
        }

        // H[row] = -sum_col s[row][col] * acc[row][col]
        // D layout: row = 4*g4 + q (reg q), col = nb*16 + lo16.
        // Re-read s fp32 from global (L1 hit, lines already fetched).
        const float* R = S + g4 * (4 * NSPIN);
        float p0 = 0.f, p1 = 0.f, p2 = 0.f, p3 = 0.f;
#pragma unroll
        for (int nb = 0; nb < 4; ++nb) {
            int col = nb * 16 + lo16;
            p0 += R[0 * NSPIN + col] * acc[nb][0];
            p1 += R[1 * NSPIN + col] * acc[nb][1];
            p2 += R[2 * NSPIN + col] * acc[nb][2];
            p3 += R[3 * NSPIN + col] * acc[nb][3];
        }
        // reduce over the 16 lanes of each g4 group (cols)
#pragma unroll
        for (int m = 1; m <= 8; m <<= 1) {
            p0 += __shfl_xor(p0, m, 64);
            p1 += __shfl_xor(p1, m, 64);
            p2 += __shfl_xor(p2, m, 64);
            p3 += __shfl_xor(p3, m, 64);
        }
        if (lo16 < 4) {
            float v = (lo16 == 0) ? p0 : (lo16 == 1) ? p1 : (lo16 == 2) ? p2 : p3;
            out[t * 16 + g4 * 4 + lo16] = -v;
        }
    }
}

extern "C" void kernel_launch(void* const* d_in, const int* in_sizes, int n_in,
                              void* d_out, int out_size, void* d_ws, size_t ws_size,
                              hipStream_t stream) {
    const float* states    = (const float*)d_in[0];
    const float* couplings = (const float*)d_in[1];
    const float* fields    = (const float*)d_in[2];
    float* out = (float*)d_out;

    if (ws_size >= NSPIN * NSPIN * sizeof(__bf16)) {
        __bf16* Jg = (__bf16*)d_ws;
        build_J_kernel<<<16, 256, 0, stream>>>(couplings, Jg);
        const int blocks = 3125;                 // 12500 waves * 5 tiles = 62500
        ham_kernel<true><<<blocks, 256, 0, stream>>>(states, couplings, fields,
                                                     Jg, out, blocks * 4);
    } else {
        const int blocks = 1024;                 // amortize per-block J build
        ham_kernel<false><<<blocks, 256, 0, stream>>>(states, couplings, fields,
                                                      nullptr, out, blocks * 4);
    }
}